// Round 1
// baseline (463.042 us; speedup 1.0000x reference)
//
#include <hip/hip_runtime.h>
#include <math.h>

#define BATCH   131072
#define OUTD    700
#define H1D     25
#define H2D     20

// ---------------- fused kernel: f64 front-end (LDS handoff) + f32 back-end ----
// 64 samples per block. Threads 0..63 each run one sample's front-end with
// arithmetic bit-identical to the previous (passing) kernel: same fma chains,
// same OCML tanh/pow, same op order. h2 (f32) + 4 scales go to LDS instead of
// global workspace; after one barrier all 256 threads run the identical f32
// back-end GEMM + scale + store. This removes the 25 MB h2f/scl round trip,
// the second launch, and lets f64-tanh latency of some blocks hide under the
// HBM-store phase of other resident blocks.
#define BLK     256
#define SPB     64                    // samples per block
#define NBLK    (BATCH / SPB)         // 2048

__global__ __launch_bounds__(BLK) void fused_kernel(
    const float* __restrict__ x,
    const float* __restrict__ W1, const float* __restrict__ b1,
    const float* __restrict__ W2, const float* __restrict__ b2,
    const float* __restrict__ W3, const float* __restrict__ b3,
    float* __restrict__ out)
{
    __shared__ double w1d[2 * H1D];
    __shared__ double b1d[H1D];
    __shared__ double w2d[H1D * H2D];
    __shared__ double b2d[H2D];
    __shared__ float  xgs[50];
    __shared__ double cwd[50];
    __shared__ double cgd[4][H2D];
    __shared__ double cbd[4];
    __shared__ __align__(16) float sh2[SPB * H2D];   // 5 KB
    __shared__ float4 ssc[SPB];                      // 1 KB

    const int t = threadIdx.x;

    // ---- stage front-end constants (identical to previous kernel) ----
    if (t < 2 * H1D) w1d[t] = (double)W1[t];
    if (t < H1D)     b1d[t] = (double)b1[t];
    for (int i = t; i < H1D * H2D; i += BLK) w2d[i] = (double)W2[i];
    if (t < H2D)     b2d[t] = (double)b2[t];
    if (t < 50) {
        // match np.logspace(-7,0,50).astype(float32); volatile blocks fma
        volatile double m = (double)t * (7.0 / 49.0);
        double e = m + (-7.0);
        xgs[t] = (t == 49) ? 1.0f : (float)pow(10.0, e);
    }
    __syncthreads();

    if (t < 50) {
        float xp = (t < 49) ? xgs[t + 1] : xgs[t];
        float xm = (t > 0)  ? xgs[t - 1] : xgs[t];
        cwd[t] = 0.5 * ((double)xp - (double)xm);
    }
    __syncthreads();

    if (t < 4 * H2D) {
        const int q = t / H2D, k = t % H2D;
        const float* col = W3 + k * OUTD;
        double acc = 0.0;
        if (q == 0) {
            for (int i = 0; i < 50; ++i)
                acc = fma(cwd[i], (double)col[50 + i] + (double)col[100 + i], acc);
        } else {
            const int off = 100 + 50 * q;
            for (int i = 0; i < 50; ++i)
                acc = fma(cwd[i], (double)col[off + i], acc);
        }
        cgd[q][k] = acc;
    }
    if (t < 4) {
        const int q = t;
        double acc = 0.0;
        if (q == 0) {
            for (int i = 0; i < 50; ++i)
                acc = fma(cwd[i], (double)b3[50 + i] + (double)b3[100 + i], acc);
        } else {
            const int off = 100 + 50 * q;
            for (int i = 0; i < 50; ++i)
                acc = fma(cwd[i], (double)b3[off + i], acc);
        }
        cbd[q] = acc;
    }
    __syncthreads();

    // ---- front-end: one sample per thread (t<64), registers only ----
    if (t < SPB) {
        const int sid = blockIdx.x * SPB + t;
        const double x0 = (double)x[sid * 2 + 0];
        const double x1 = (double)x[sid * 2 + 1];

        double h1[H1D];
        #pragma unroll
        for (int k = 0; k < H1D; ++k)
            h1[k] = tanh(fma(x0, w1d[k], fma(x1, w1d[H1D + k], b1d[k])));

        double h2[H2D];
        #pragma unroll
        for (int m = 0; m < H2D; ++m) {
            double acc = b2d[m];
            #pragma unroll
            for (int k = 0; k < H1D; ++k) acc = fma(h1[k], w2d[k * H2D + m], acc);
            h2[m] = tanh(acc);
        }

        float4 sv;
        float* svp = (float*)&sv;
        #pragma unroll
        for (int q = 0; q < 4; ++q) {
            double acc = cbd[q];
            #pragma unroll
            for (int k = 0; k < H2D; ++k) acc = fma(h2[k], cgd[q][k], acc);
            const double num = (q & 1) ? 3.0 : 1.0;   // 1/g, 3/v, 1/v3, 3/v8
            svp[q] = (float)(num / acc);
        }
        ssc[t] = sv;

        float4* h2o = (float4*)(&sh2[t * H2D]);
        #pragma unroll
        for (int q5 = 0; q5 < 5; ++q5) {
            float4 v;
            v.x = (float)h2[4 * q5 + 0]; v.y = (float)h2[4 * q5 + 1];
            v.z = (float)h2[4 * q5 + 2]; v.w = (float)h2[4 * q5 + 3];
            h2o[q5] = v;
        }
    }
    __syncthreads();

    // ---- back-end: identical f32 GEMM + scale + store ----
    // W3 column registers loaded AFTER the front-end phase so peak VGPR
    // pressure stays low (f64 h1/h2 arrays are dead by here).
    float w3r[3][H2D];
    float b3r[3];
    #pragma unroll
    for (int c = 0; c < 3; ++c) {
        const int j = t + BLK * c;
        if (j < OUTD) {
            b3r[c] = b3[j];
            #pragma unroll
            for (int k = 0; k < H2D; ++k) w3r[c][k] = W3[k * OUTD + j];
        } else {
            b3r[c] = 0.0f;
            #pragma unroll
            for (int k = 0; k < H2D; ++k) w3r[c][k] = 0.0f;
        }
    }

    int bkt[3];
    #pragma unroll
    for (int c = 0; c < 3; ++c) {
        const int j = t + BLK * c;
        int b = 0;
        if      (j >= 50  && j < 150) b = 1;
        else if (j >= 150 && j < 200) b = 2;
        else if (j >= 200 && j < 250) b = 3;
        else if (j >= 250 && j < 300) b = 4;
        bkt[c] = b;
    }

    const size_t rowbase = (size_t)blockIdx.x * SPB * OUTD;

    for (int s = 0; s < SPB; ++s) {
        float h[H2D];
        #pragma unroll
        for (int q5 = 0; q5 < 5; ++q5) {
            const float4 hv = *reinterpret_cast<const float4*>(&sh2[s * H2D + 4 * q5]);
            h[4 * q5 + 0] = hv.x; h[4 * q5 + 1] = hv.y;
            h[4 * q5 + 2] = hv.z; h[4 * q5 + 3] = hv.w;
        }
        const float4 sv = ssc[s];
        const size_t row = rowbase + (size_t)s * OUTD;
        #pragma unroll
        for (int c = 0; c < 3; ++c) {
            const int j = t + BLK * c;
            if (j < OUTD) {
                float acc = b3r[c];
                #pragma unroll
                for (int k = 0; k < H2D; ++k) acc = fmaf(h[k], w3r[c][k], acc);
                float sc = 1.0f;
                if      (bkt[c] == 1) sc = sv.x;
                else if (bkt[c] == 2) sc = sv.y;
                else if (bkt[c] == 3) sc = sv.z;
                else if (bkt[c] == 4) sc = sv.w;
                out[row + j] = acc * sc;
            }
        }
    }
}

extern "C" void kernel_launch(void* const* d_in, const int* in_sizes, int n_in,
                              void* d_out, int out_size, void* d_ws, size_t ws_size,
                              hipStream_t stream) {
    const float* x  = (const float*)d_in[0];
    const float* W1 = (const float*)d_in[1];
    const float* b1 = (const float*)d_in[2];
    const float* W2 = (const float*)d_in[3];
    const float* b2 = (const float*)d_in[4];
    const float* W3 = (const float*)d_in[5];
    const float* b3 = (const float*)d_in[6];
    float* out = (float*)d_out;

    hipLaunchKernelGGL(fused_kernel, dim3(NBLK), dim3(BLK), 0, stream,
                       x, W1, b1, W2, b2, W3, b3, out);
}

// Round 2
// 439.985 us; speedup vs baseline: 1.0524x; 1.0524x over previous
//
#include <hip/hip_runtime.h>
#include <math.h>

#define BATCH   131072
#define OUTD    700
#define H1D     25
#define H2D     20

// ---------------- fused kernel: 4-way-split f64 front-end + f32 back-end ----
// 64 samples per block, 256 threads. Front-end work for sample s is split
// across the 4 threads {s, s+64, s+128, s+192}: thread q computes h1[k] for
// k%4==q, h2[m] for m%4==q, and scale q. Each individual output value is
// produced by the EXACT same fma/tanh chain (same order, same ops) as the
// previous passing kernel -> bit-identical results. This moves the ~45
// f64-tanh-per-sample critical path from 1 wave to all 4 waves of the block.
#define BLK     256
#define SPB     64                    // samples per block
#define NBLK    (BATCH / SPB)         // 2048

// padded LDS strides (doubles) to keep strided cross-sample access <=2-way
#define S1PAD   27
#define S2PAD   21

__global__ __launch_bounds__(BLK) void fused_kernel(
    const float* __restrict__ x,
    const float* __restrict__ W1, const float* __restrict__ b1,
    const float* __restrict__ W2, const float* __restrict__ b2,
    const float* __restrict__ W3, const float* __restrict__ b3,
    float* __restrict__ out)
{
    __shared__ double w1d[2 * H1D];
    __shared__ double b1d[H1D];
    __shared__ double w2d[H1D * H2D];
    __shared__ double b2d[H2D];
    __shared__ float  xgs[50];
    __shared__ double cwd[50];
    __shared__ double cgd[4][H2D];
    __shared__ double cbd[4];
    __shared__ double sh1d[SPB * S1PAD];              // 13.8 KB: h1 (f64)
    __shared__ double sh2d[SPB * S2PAD];              // 10.8 KB: h2 (f64)
    __shared__ __align__(16) float sh2f[SPB * H2D];   // 5 KB: h2 (f32) for back-end
    __shared__ __align__(16) float ssc4[SPB * 4];     // 1 KB: scales

    const int t  = threadIdx.x;
    const int ls = t & 63;       // sample within block
    const int lq = t >> 6;       // 0..3: which quarter of the front-end work

    // ---- stage front-end constants (identical to previous kernel) ----
    if (t < 2 * H1D) w1d[t] = (double)W1[t];
    if (t < H1D)     b1d[t] = (double)b1[t];
    for (int i = t; i < H1D * H2D; i += BLK) w2d[i] = (double)W2[i];
    if (t < H2D)     b2d[t] = (double)b2[t];
    if (t < 50) {
        // match np.logspace(-7,0,50).astype(float32); volatile blocks fma
        volatile double m = (double)t * (7.0 / 49.0);
        double e = m + (-7.0);
        xgs[t] = (t == 49) ? 1.0f : (float)pow(10.0, e);
    }
    __syncthreads();

    if (t < 50) {
        float xp = (t < 49) ? xgs[t + 1] : xgs[t];
        float xm = (t > 0)  ? xgs[t - 1] : xgs[t];
        cwd[t] = 0.5 * ((double)xp - (double)xm);
    }
    __syncthreads();

    if (t < 4 * H2D) {
        const int q = t / H2D, k = t % H2D;
        const float* col = W3 + k * OUTD;
        double acc = 0.0;
        if (q == 0) {
            for (int i = 0; i < 50; ++i)
                acc = fma(cwd[i], (double)col[50 + i] + (double)col[100 + i], acc);
        } else {
            const int off = 100 + 50 * q;
            for (int i = 0; i < 50; ++i)
                acc = fma(cwd[i], (double)col[off + i], acc);
        }
        cgd[q][k] = acc;
    }
    if (t < 4) {
        const int q = t;
        double acc = 0.0;
        if (q == 0) {
            for (int i = 0; i < 50; ++i)
                acc = fma(cwd[i], (double)b3[50 + i] + (double)b3[100 + i], acc);
        } else {
            const int off = 100 + 50 * q;
            for (int i = 0; i < 50; ++i)
                acc = fma(cwd[i], (double)b3[off + i], acc);
        }
        cbd[q] = acc;
    }
    __syncthreads();

    // ---- F1: h1[k] for k%4==lq (independent chains; same expression) ----
    {
        const int sid = blockIdx.x * SPB + ls;
        const double x0 = (double)x[sid * 2 + 0];
        const double x1 = (double)x[sid * 2 + 1];
        for (int k = lq; k < H1D; k += 4)
            sh1d[ls * S1PAD + k] =
                tanh(fma(x0, w1d[k], fma(x1, w1d[H1D + k], b1d[k])));
    }
    __syncthreads();

    // ---- F2: h2[m] for m%4==lq; k-chain in original order k=0..24 ----
    {
        double acc2[5];
        #pragma unroll
        for (int i = 0; i < 5; ++i) acc2[i] = b2d[4 * i + lq];
        for (int k = 0; k < H1D; ++k) {
            const double hk = sh1d[ls * S1PAD + k];
            #pragma unroll
            for (int i = 0; i < 5; ++i)
                acc2[i] = fma(hk, w2d[k * H2D + 4 * i + lq], acc2[i]);
        }
        #pragma unroll
        for (int i = 0; i < 5; ++i) {
            const double h2v = tanh(acc2[i]);
            sh2d[ls * S2PAD + 4 * i + lq] = h2v;
            sh2f[ls * H2D  + 4 * i + lq] = (float)h2v;
        }
    }
    __syncthreads();

    // ---- F3: scale lq for sample ls; exact original 20-fma chain ----
    {
        double acc = cbd[lq];
        #pragma unroll
        for (int k = 0; k < H2D; ++k)
            acc = fma(sh2d[ls * S2PAD + k], cgd[lq][k], acc);
        const double num = (lq & 1) ? 3.0 : 1.0;   // 1/g, 3/v, 1/v3, 3/v8
        ssc4[ls * 4 + lq] = (float)(num / acc);
    }
    __syncthreads();

    // ---- back-end: identical f32 GEMM + scale + store ----
    // W3 column registers loaded AFTER the front-end phase so peak VGPR
    // pressure stays low (f64 state is dead by here).
    float w3r[3][H2D];
    float b3r[3];
    #pragma unroll
    for (int c = 0; c < 3; ++c) {
        const int j = t + BLK * c;
        if (j < OUTD) {
            b3r[c] = b3[j];
            #pragma unroll
            for (int k = 0; k < H2D; ++k) w3r[c][k] = W3[k * OUTD + j];
        } else {
            b3r[c] = 0.0f;
            #pragma unroll
            for (int k = 0; k < H2D; ++k) w3r[c][k] = 0.0f;
        }
    }

    int bkt[3];
    #pragma unroll
    for (int c = 0; c < 3; ++c) {
        const int j = t + BLK * c;
        int b = 0;
        if      (j >= 50  && j < 150) b = 1;
        else if (j >= 150 && j < 200) b = 2;
        else if (j >= 200 && j < 250) b = 3;
        else if (j >= 250 && j < 300) b = 4;
        bkt[c] = b;
    }

    const size_t rowbase = (size_t)blockIdx.x * SPB * OUTD;

    for (int s = 0; s < SPB; ++s) {
        float h[H2D];
        #pragma unroll
        for (int q5 = 0; q5 < 5; ++q5) {
            const float4 hv = *reinterpret_cast<const float4*>(&sh2f[s * H2D + 4 * q5]);
            h[4 * q5 + 0] = hv.x; h[4 * q5 + 1] = hv.y;
            h[4 * q5 + 2] = hv.z; h[4 * q5 + 3] = hv.w;
        }
        const float4 sv = *reinterpret_cast<const float4*>(&ssc4[s * 4]);
        const size_t row = rowbase + (size_t)s * OUTD;
        #pragma unroll
        for (int c = 0; c < 3; ++c) {
            const int j = t + BLK * c;
            if (j < OUTD) {
                float acc = b3r[c];
                #pragma unroll
                for (int k = 0; k < H2D; ++k) acc = fmaf(h[k], w3r[c][k], acc);
                float sc = 1.0f;
                if      (bkt[c] == 1) sc = sv.x;
                else if (bkt[c] == 2) sc = sv.y;
                else if (bkt[c] == 3) sc = sv.z;
                else if (bkt[c] == 4) sc = sv.w;
                out[row + j] = acc * sc;
            }
        }
    }
}

extern "C" void kernel_launch(void* const* d_in, const int* in_sizes, int n_in,
                              void* d_out, int out_size, void* d_ws, size_t ws_size,
                              hipStream_t stream) {
    const float* x  = (const float*)d_in[0];
    const float* W1 = (const float*)d_in[1];
    const float* b1 = (const float*)d_in[2];
    const float* W2 = (const float*)d_in[3];
    const float* b2 = (const float*)d_in[4];
    const float* W3 = (const float*)d_in[5];
    const float* b3 = (const float*)d_in[6];
    float* out = (float*)d_out;

    hipLaunchKernelGGL(fused_kernel, dim3(NBLK), dim3(BLK), 0, stream,
                       x, W1, b1, W2, b2, W3, b3, out);
}